// Round 12
// baseline (75.586 us; speedup 1.0000x reference)
//
#include <hip/hip_runtime.h>
#include <hip/hip_bf16.h>

#define N 192
#define CZ 128
#define NH 4
#define CH 32
#define WIN 16
#define NROWS (N*N)   // 36864

typedef __attribute__((ext_vector_type(8))) short bf16x8;
typedef __attribute__((ext_vector_type(4))) float f32x4;

static __device__ __forceinline__ ushort f2bf(float x){
    union{float f; unsigned u;} a; a.f = x;
    unsigned r = a.u + 0x7fffu + ((a.u>>16)&1u);   // RNE
    return (ushort)(r>>16);
}
static __device__ __forceinline__ float bf2f(ushort s){
    union{unsigned u; float f;} a; a.u = ((unsigned)s)<<16;
    return a.f;
}

// ---------------- K1: LayerNorm -> zl(bf16) + tb(f32) ----------------
__global__ __launch_bounds__(256) void k_ln(
    const float* __restrict__ z, const float* __restrict__ lnw, const float* __restrict__ lnb,
    const float* __restrict__ wbias, ushort* __restrict__ zl, float* __restrict__ tb)
{
    const int tid = threadIdx.x;
    const int wave = tid >> 6, lane = tid & 63;
    const int r  = wave*4 + (lane >> 4);
    const int li = lane & 15;
    const int row = blockIdx.x*16 + r;
    const float* zr = z + (size_t)row*CZ + li*8;
    float4 a = ((const float4*)zr)[0];
    float4 b = ((const float4*)zr)[1];
    float s  = a.x+a.y+a.z+a.w + b.x+b.y+b.z+b.w;
    float s2 = a.x*a.x+a.y*a.y+a.z*a.z+a.w*a.w + b.x*b.x+b.y*b.y+b.z*b.z+b.w*b.w;
    #pragma unroll
    for (int off=1; off<16; off<<=1) { s += __shfl_xor(s, off); s2 += __shfl_xor(s2, off); }
    const float mu   = s * (1.f/CZ);
    const float rstd = rsqrtf(s2*(1.f/CZ) - mu*mu + 1e-5f);
    const int c0 = li*8;
    float vals[8] = {a.x,a.y,a.z,a.w,b.x,b.y,b.z,b.w};
    float tbp[4] = {0.f,0.f,0.f,0.f};
    uint4 pk; ushort* ph = (ushort*)&pk;
    #pragma unroll
    for (int t=0; t<8; t++) {
        const float nv = (vals[t]-mu)*rstd*lnw[c0+t] + lnb[c0+t];
        ph[t] = f2bf(nv);
        float4 wb4 = *(const float4*)(wbias + (c0+t)*4);
        tbp[0] += nv*wb4.x; tbp[1] += nv*wb4.y;
        tbp[2] += nv*wb4.z; tbp[3] += nv*wb4.w;
    }
    *(uint4*)(zl + (size_t)row*CZ + c0) = pk;
    #pragma unroll
    for (int off=1; off<16; off<<=1) {
        #pragma unroll
        for (int h=0; h<4; h++) tbp[h] += __shfl_xor(tbp[h], off);
    }
    if (li == 0) *(float4*)(tb + (size_t)row*4) = make_float4(tbp[0],tbp[1],tbp[2],tbp[3]);
}

// ---------------- K2: MFMA projections, register-B, C^T store repack ----------------
// grid = 4 matrices x 288 row-blocks (1152). Block = 4 waves, no barriers.
// Wave w owns cols [w*32, w*32+32). C^T via swapped MFMA + per-wave LDS repack
// -> full 64B-sector dwordx4 stores.
__global__ __launch_bounds__(256, 4) void k_gemm(
    const ushort* __restrict__ zl,
    const float* __restrict__ wq, const float* __restrict__ wk,
    const float* __restrict__ wv, const float* __restrict__ wg,
    const float* __restrict__ bg,
    ushort* __restrict__ q, ushort* __restrict__ k,
    ushort* __restrict__ v, ushort* __restrict__ g)
{
    __shared__ ushort st[4][16][36];    // per-wave store-repack scratch
    const int bid  = blockIdx.x;
    const int m    = bid & 3;
    const int rblk = bid >> 2;
    const float* W = (m==0)?wq:(m==1)?wk:(m==2)?wv:wg;
    ushort*      O = (m==0)?q :(m==1)?k :(m==2)?v :g;
    const int tid = threadIdx.x;
    const int wid = tid >> 6, lane = tid & 63;
    const int l16 = lane & 15, lk = lane >> 4;

    bf16x8 bfrag[2][4];
    float4 bg4[2];
    #pragma unroll
    for (int nt2=0; nt2<2; nt2++) {
        const int col = wid*32 + nt2*16 + l16;
        #pragma unroll
        for (int ks=0; ks<4; ks++) {
            ushort tmp[8];
            #pragma unroll
            for (int i=0; i<8; i++)
                tmp[i] = f2bf(W[(size_t)(ks*32 + lk*8 + i)*CZ + col]);
            bfrag[nt2][ks] = *(const bf16x8*)tmp;
        }
        if (m == 3) bg4[nt2] = *(const float4*)(bg + wid*32 + nt2*16 + lk*4);
    }

    #pragma unroll 1
    for (int rt=0; rt<8; rt++) {
        const int row0 = rblk*128 + rt*16;
        bf16x8 af[4];
        #pragma unroll
        for (int ks=0; ks<4; ks++)
            af[ks] = *(const bf16x8*)(zl + (size_t)(row0 + l16)*CZ + ks*32 + lk*8);
        #pragma unroll
        for (int nt2=0; nt2<2; nt2++) {
            f32x4 acc = {0.f,0.f,0.f,0.f};
            #pragma unroll
            for (int ks=0; ks<4; ks++)   // swapped args -> C^T fragment layout
                acc = __builtin_amdgcn_mfma_f32_16x16x32_bf16(bfrag[nt2][ks], af[ks], acc, 0, 0, 0);
            // thread holds row (rt*16+l16), cols wid*32+nt2*16+lk*4 .. +3
            float v0,v1,v2,v3;
            if (m == 3) {
                v0 = 1.f/(1.f + __expf(-(acc[0] + bg4[nt2].x)));
                v1 = 1.f/(1.f + __expf(-(acc[1] + bg4[nt2].y)));
                v2 = 1.f/(1.f + __expf(-(acc[2] + bg4[nt2].z)));
                v3 = 1.f/(1.f + __expf(-(acc[3] + bg4[nt2].w)));
            } else { v0=acc[0]; v1=acc[1]; v2=acc[2]; v3=acc[3]; }
            uint2 pk2;
            pk2.x = (unsigned)f2bf(v0) | ((unsigned)f2bf(v1)<<16);
            pk2.y = (unsigned)f2bf(v2) | ((unsigned)f2bf(v3)<<16);
            *(uint2*)&st[wid][l16][nt2*16 + lk*4] = pk2;
        }
        // readback: 4 lanes x 16B = full 64B sector per row (in-wave DS ordering)
        const int row = lane >> 2, c8 = lane & 3;
        uint4 ov = *(const uint4*)&st[wid][row][c8*8];
        *(uint4*)(O + (size_t)(rblk*128 + rt*16 + row)*CZ + wid*32 + c8*8) = ov;
    }
}

// ---------------- K3: windowed attention + gate + out-GEMM fused ----------------
__global__ __launch_bounds__(256, 3) void k_attn_out(
    const ushort* __restrict__ q, const ushort* __restrict__ k, const ushort* __restrict__ v,
    const ushort* __restrict__ g, const float* __restrict__ tb, const float* __restrict__ mask,
    const float* __restrict__ wout, const float* __restrict__ bout, float* __restrict__ out)
{
    __shared__ float kl[47][NH][33];
    __shared__ float vl[47][NH][33];
    __shared__ float ml[47];
    ushort (*po)[132] = (ushort (*)[132])&kl[0][0][0];   // aliases kl after barrier

    const int i   = blockIdx.y;
    const int j0  = blockIdx.x * 32;
    const int tid = threadIdx.x;

    for (int idx = tid; idx < 47*16; idx += 256) {
        const int row = idx >> 4, c8 = idx & 15;
        const int jj  = j0 - 8 + row;
        const int jjc = min(max(jj, 0), N-1);
        const size_t goff = ((size_t)i*N + jjc)*CZ + c8*8;
        uint4 ku = *(const uint4*)(k + goff);
        uint4 vu = *(const uint4*)(v + goff);
        const int hh = c8 >> 2, co = (c8 & 3)*8;
        const ushort* ks_ = (const ushort*)&ku;
        const ushort* vs_ = (const ushort*)&vu;
        #pragma unroll
        for (int t=0; t<8; t++) {
            kl[row][hh][co+t] = bf2f(ks_[t]);
            vl[row][hh][co+t] = bf2f(vs_[t]);
        }
    }
    if (tid < 47) {
        const int jj  = j0 - 8 + tid;
        const int jjc = min(max(jj, 0), N-1);
        const bool ok = (jj >= 0) && (jj < N) && (mask[(size_t)i*N + jjc] > 0.f);
        ml[tid] = ok ? 0.f : -1e9f;
    }
    __syncthreads();

    const int chalf = tid & 1;
    const int h     = (tid >> 1) & 3;
    const int jloc  = tid >> 3;
    const int j     = j0 + jloc;
    const int c0l   = chalf * 16;
    const size_t base = ((size_t)i*N + j)*CZ + h*CH + c0l;

    float qv[16];
    {
        uint4 q1 = *(const uint4*)(q + base);
        uint4 q2 = *(const uint4*)(q + base + 8);
        const ushort* s1 = (const ushort*)&q1;
        const ushort* s2 = (const ushort*)&q2;
        #pragma unroll
        for (int t=0; t<8; t++) { qv[t] = bf2f(s1[t]); qv[8+t] = bf2f(s2[t]); }
    }

    const float scale = 0.17677669529663688f; // 1/sqrt(32)
    float lg[WIN];
    #pragma unroll
    for (int w=0; w<WIN; w++) {
        const int rel = jloc + w;
        float dot = 0.f;
        #pragma unroll
        for (int c4=0; c4<4; c4++) {
            float4 kv = *(const float4*)&kl[rel][h][c0l + c4*4];
            dot += qv[c4*4+0]*kv.x + qv[c4*4+1]*kv.y + qv[c4*4+2]*kv.z + qv[c4*4+3]*kv.w;
        }
        dot += __shfl_xor(dot, 1);
        const int jj  = j - 8 + w;
        const int jjc = min(max(jj, 0), N-1);
        lg[w] = dot*scale + tb[((size_t)j*N + jjc)*4 + h] + ml[rel];
    }
    float mx = lg[0];
    #pragma unroll
    for (int w=1; w<WIN; w++) mx = fmaxf(mx, lg[w]);
    float sum = 0.f;
    #pragma unroll
    for (int w=0; w<WIN; w++) { lg[w] = __expf(lg[w]-mx); sum += lg[w]; }
    const float inv = 1.f/sum;

    float o[16];
    #pragma unroll
    for (int c=0; c<16; c++) o[c] = 0.f;
    #pragma unroll
    for (int w=0; w<WIN; w++) {
        const float p   = lg[w]*inv;
        const int   rel = jloc + w;
        #pragma unroll
        for (int c4=0; c4<4; c4++) {
            float4 vv = *(const float4*)&vl[rel][h][c0l + c4*4];
            o[c4*4+0] += p*vv.x; o[c4*4+1] += p*vv.y;
            o[c4*4+2] += p*vv.z; o[c4*4+3] += p*vv.w;
        }
    }

    uint4 o1, o2;
    {
        uint4 g1 = *(const uint4*)(g + base);
        uint4 g2 = *(const uint4*)(g + base + 8);
        const ushort* s1 = (const ushort*)&g1;
        const ushort* s2 = (const ushort*)&g2;
        ushort* p1 = (ushort*)&o1; ushort* p2 = (ushort*)&o2;
        #pragma unroll
        for (int t=0; t<8; t++) {
            p1[t] = f2bf(o[t]   * bf2f(s1[t]));
            p2[t] = f2bf(o[8+t] * bf2f(s2[t]));
        }
    }
    __syncthreads();                 // all kl/vl reads done -> safe to overwrite with po
    *(uint4*)&po[jloc][h*CH + c0l]     = o1;
    *(uint4*)&po[jloc][h*CH + c0l + 8] = o2;

    // ---- out-GEMM: wave owns cols [wid*32, wid*32+32) ----
    const int wid = tid >> 6, lane = tid & 63;
    const int l16 = lane & 15, lk = lane >> 4;
    bf16x8 bfrag[2][4];
    float4 bo4[2];
    #pragma unroll
    for (int nt2=0; nt2<2; nt2++) {
        const int col = wid*32 + nt2*16 + l16;
        #pragma unroll
        for (int ks=0; ks<4; ks++) {
            ushort tmp[8];
            #pragma unroll
            for (int t=0; t<8; t++)
                tmp[t] = f2bf(wout[(size_t)(ks*32 + lk*8 + t)*CZ + col]);
            bfrag[nt2][ks] = *(const bf16x8*)tmp;
        }
        bo4[nt2] = *(const float4*)(bout + wid*32 + nt2*16 + lk*4);
    }
    __syncthreads();

    #pragma unroll
    for (int rt=0; rt<2; rt++) {
        bf16x8 af[4];
        #pragma unroll
        for (int ks=0; ks<4; ks++)
            af[ks] = *(const bf16x8*)&po[rt*16 + l16][ks*32 + lk*8];
        const size_t orow = (size_t)(i*N + j0 + rt*16 + l16)*CZ;
        #pragma unroll
        for (int nt2=0; nt2<2; nt2++) {
            f32x4 acc = {0.f,0.f,0.f,0.f};
            #pragma unroll
            for (int ks=0; ks<4; ks++)   // swapped -> C^T: row=l16, 4 consecutive cols
                acc = __builtin_amdgcn_mfma_f32_16x16x32_bf16(bfrag[nt2][ks], af[ks], acc, 0, 0, 0);
            float4 ov;
            ov.x = acc[0] + bo4[nt2].x; ov.y = acc[1] + bo4[nt2].y;
            ov.z = acc[2] + bo4[nt2].z; ov.w = acc[3] + bo4[nt2].w;
            *(float4*)(out + orow + wid*32 + nt2*16 + lk*4) = ov;
        }
    }
}

extern "C" void kernel_launch(void* const* d_in, const int* in_sizes, int n_in,
                              void* d_out, int out_size, void* d_ws, size_t ws_size,
                              hipStream_t stream)
{
    const float* z    = (const float*)d_in[0];
    const float* mask = (const float*)d_in[1];
    const float* lnw  = (const float*)d_in[2];
    const float* lnb  = (const float*)d_in[3];
    const float* wq   = (const float*)d_in[4];
    const float* wk   = (const float*)d_in[5];
    const float* wv   = (const float*)d_in[6];
    const float* wb   = (const float*)d_in[7];
    const float* wg   = (const float*)d_in[8];
    const float* bg   = (const float*)d_in[9];
    const float* wo   = (const float*)d_in[10];
    const float* bo   = (const float*)d_in[11];

    const size_t NE = (size_t)NROWS*CZ;
    ushort* zl = (ushort*)d_ws;          // bf16 [NROWS][128]
    ushort* q  = zl + NE;
    ushort* k  = q + NE;
    ushort* v  = k + NE;
    ushort* g  = v + NE;
    float*  tb = (float*)(g + NE);       // f32 [NROWS][4]
    if (ws_size < 5*NE*sizeof(ushort) + (size_t)NROWS*4*sizeof(float)) return;

    k_ln  <<<NROWS/16, 256, 0, stream>>>(z, lnw, lnb, wb, zl, tb);
    k_gemm<<<4*(NROWS/128), 256, 0, stream>>>(zl, wq, wk, wv, wg, bg, q, k, v, g);
    k_attn_out<<<dim3(N/32, N), 256, 0, stream>>>(q, k, v, g, tb, mask, wo, bo, (float*)d_out);
}

// Round 13
// 72.798 us; speedup vs baseline: 1.0383x; 1.0383x over previous
//
#include <hip/hip_runtime.h>
#include <hip/hip_bf16.h>

#define N 192
#define CZ 128
#define NH 4
#define CH 32
#define WIN 16
#define NROWS (N*N)   // 36864

typedef __attribute__((ext_vector_type(8))) short bf16x8;
typedef __attribute__((ext_vector_type(4))) float f32x4;

static __device__ __forceinline__ ushort f2bf(float x){
    union{float f; unsigned u;} a; a.f = x;
    unsigned r = a.u + 0x7fffu + ((a.u>>16)&1u);   // RNE
    return (ushort)(r>>16);
}
static __device__ __forceinline__ float bf2f(ushort s){
    union{unsigned u; float f;} a; a.u = ((unsigned)s)<<16;
    return a.f;
}

// ---------------- K1: LayerNorm -> zl(bf16) + tb(f32) ----------------
__global__ __launch_bounds__(256) void k_ln(
    const float* __restrict__ z, const float* __restrict__ lnw, const float* __restrict__ lnb,
    const float* __restrict__ wbias, ushort* __restrict__ zl, float* __restrict__ tb)
{
    const int tid = threadIdx.x;
    const int wave = tid >> 6, lane = tid & 63;
    const int r  = wave*4 + (lane >> 4);
    const int li = lane & 15;
    const int row = blockIdx.x*16 + r;
    const float* zr = z + (size_t)row*CZ + li*8;
    float4 a = ((const float4*)zr)[0];
    float4 b = ((const float4*)zr)[1];
    float s  = a.x+a.y+a.z+a.w + b.x+b.y+b.z+b.w;
    float s2 = a.x*a.x+a.y*a.y+a.z*a.z+a.w*a.w + b.x*b.x+b.y*b.y+b.z*b.z+b.w*b.w;
    #pragma unroll
    for (int off=1; off<16; off<<=1) { s += __shfl_xor(s, off); s2 += __shfl_xor(s2, off); }
    const float mu   = s * (1.f/CZ);
    const float rstd = rsqrtf(s2*(1.f/CZ) - mu*mu + 1e-5f);
    const int c0 = li*8;
    float vals[8] = {a.x,a.y,a.z,a.w,b.x,b.y,b.z,b.w};
    float tbp[4] = {0.f,0.f,0.f,0.f};
    uint4 pk; ushort* ph = (ushort*)&pk;
    #pragma unroll
    for (int t=0; t<8; t++) {
        const float nv = (vals[t]-mu)*rstd*lnw[c0+t] + lnb[c0+t];
        ph[t] = f2bf(nv);
        float4 wb4 = *(const float4*)(wbias + (c0+t)*4);
        tbp[0] += nv*wb4.x; tbp[1] += nv*wb4.y;
        tbp[2] += nv*wb4.z; tbp[3] += nv*wb4.w;
    }
    *(uint4*)(zl + (size_t)row*CZ + c0) = pk;
    #pragma unroll
    for (int off=1; off<16; off<<=1) {
        #pragma unroll
        for (int h=0; h<4; h++) tbp[h] += __shfl_xor(tbp[h], off);
    }
    if (li == 0) *(float4*)(tb + (size_t)row*4) = make_float4(tbp[0],tbp[1],tbp[2],tbp[3]);
}

// ---------------- K2: MFMA projections, register-B, pipelined A (MLP fix) ----------------
// grid = 4 matrices x 288 row-blocks. Wave w owns cols [w*32,w*32+32).
// A-fragments double-buffered 2-tiles-deep: 8-16 b128 loads in flight vs 4 before.
__global__ __launch_bounds__(256, 3) void k_gemm(
    const ushort* __restrict__ zl,
    const float* __restrict__ wq, const float* __restrict__ wk,
    const float* __restrict__ wv, const float* __restrict__ wg,
    const float* __restrict__ bg,
    ushort* __restrict__ q, ushort* __restrict__ k,
    ushort* __restrict__ v, ushort* __restrict__ g)
{
    __shared__ ushort st[4][16][36];    // per-wave store-repack scratch
    const int bid  = blockIdx.x;
    const int m    = bid & 3;
    const int rblk = bid >> 2;
    const float* W = (m==0)?wq:(m==1)?wk:(m==2)?wv:wg;
    ushort*      O = (m==0)?q :(m==1)?k :(m==2)?v :g;
    const int tid = threadIdx.x;
    const int wid = tid >> 6, lane = tid & 63;
    const int l16 = lane & 15, lk = lane >> 4;

    bf16x8 bfrag[2][4];
    float4 bg4[2];
    #pragma unroll
    for (int nt2=0; nt2<2; nt2++) {
        const int col = wid*32 + nt2*16 + l16;
        #pragma unroll
        for (int ks=0; ks<4; ks++) {
            ushort tmp[8];
            #pragma unroll
            for (int i=0; i<8; i++)
                tmp[i] = f2bf(W[(size_t)(ks*32 + lk*8 + i)*CZ + col]);
            bfrag[nt2][ks] = *(const bf16x8*)tmp;
        }
        if (m == 3) bg4[nt2] = *(const float4*)(bg + wid*32 + nt2*16 + lk*4);
    }

    const ushort* Abase = zl + (size_t)(rblk*128 + l16)*CZ + lk*8;

    auto loadA = [&](bf16x8 (&A)[2][4], int b) {
        #pragma unroll
        for (int t=0; t<2; t++)
            #pragma unroll
            for (int ks=0; ks<4; ks++)
                A[t][ks] = *(const bf16x8*)(Abase + (size_t)((b*2+t)*16)*CZ + ks*32);
    };
    auto computeTile = [&](bf16x8 (&A)[4], int rt) {
        #pragma unroll
        for (int nt2=0; nt2<2; nt2++) {
            f32x4 acc = {0.f,0.f,0.f,0.f};
            #pragma unroll
            for (int ks=0; ks<4; ks++)   // swapped args -> C^T fragment layout
                acc = __builtin_amdgcn_mfma_f32_16x16x32_bf16(bfrag[nt2][ks], A[ks], acc, 0, 0, 0);
            float v0,v1,v2,v3;
            if (m == 3) {
                v0 = 1.f/(1.f + __expf(-(acc[0] + bg4[nt2].x)));
                v1 = 1.f/(1.f + __expf(-(acc[1] + bg4[nt2].y)));
                v2 = 1.f/(1.f + __expf(-(acc[2] + bg4[nt2].z)));
                v3 = 1.f/(1.f + __expf(-(acc[3] + bg4[nt2].w)));
            } else { v0=acc[0]; v1=acc[1]; v2=acc[2]; v3=acc[3]; }
            uint2 pk2;
            pk2.x = (unsigned)f2bf(v0) | ((unsigned)f2bf(v1)<<16);
            pk2.y = (unsigned)f2bf(v2) | ((unsigned)f2bf(v3)<<16);
            *(uint2*)&st[wid][l16][nt2*16 + lk*4] = pk2;
        }
        // readback: 4 lanes x 16B = full 64B sector per row (in-wave DS ordering)
        const int row = lane >> 2, c8 = lane & 3;
        uint4 ov = *(const uint4*)&st[wid][row][c8*8];
        *(uint4*)(O + (size_t)(rblk*128 + rt*16 + row)*CZ + wid*32 + c8*8) = ov;
    };

    bf16x8 aA[2][4], aB[2][4];
    loadA(aA, 0); loadA(aB, 1);          // 16 b128 loads in flight
    computeTile(aA[0], 0); computeTile(aA[1], 1);
    loadA(aA, 2);                        // prefetch tiles 4,5 while aB pending
    computeTile(aB[0], 2); computeTile(aB[1], 3);
    loadA(aB, 3);                        // prefetch tiles 6,7
    computeTile(aA[0], 4); computeTile(aA[1], 5);
    computeTile(aB[0], 6); computeTile(aB[1], 7);
}

// ---------------- K3: windowed attention + gate + out-GEMM fused ----------------
__global__ __launch_bounds__(256, 3) void k_attn_out(
    const ushort* __restrict__ q, const ushort* __restrict__ k, const ushort* __restrict__ v,
    const ushort* __restrict__ g, const float* __restrict__ tb, const float* __restrict__ mask,
    const float* __restrict__ wout, const float* __restrict__ bout, float* __restrict__ out)
{
    __shared__ float kl[47][NH][33];
    __shared__ float vl[47][NH][33];
    __shared__ float ml[47];
    ushort (*po)[132] = (ushort (*)[132])&kl[0][0][0];   // aliases kl after barrier

    const int i   = blockIdx.y;
    const int j0  = blockIdx.x * 32;
    const int tid = threadIdx.x;

    for (int idx = tid; idx < 47*16; idx += 256) {
        const int row = idx >> 4, c8 = idx & 15;
        const int jj  = j0 - 8 + row;
        const int jjc = min(max(jj, 0), N-1);
        const size_t goff = ((size_t)i*N + jjc)*CZ + c8*8;
        uint4 ku = *(const uint4*)(k + goff);
        uint4 vu = *(const uint4*)(v + goff);
        const int hh = c8 >> 2, co = (c8 & 3)*8;
        const ushort* ks_ = (const ushort*)&ku;
        const ushort* vs_ = (const ushort*)&vu;
        #pragma unroll
        for (int t=0; t<8; t++) {
            kl[row][hh][co+t] = bf2f(ks_[t]);
            vl[row][hh][co+t] = bf2f(vs_[t]);
        }
    }
    if (tid < 47) {
        const int jj  = j0 - 8 + tid;
        const int jjc = min(max(jj, 0), N-1);
        const bool ok = (jj >= 0) && (jj < N) && (mask[(size_t)i*N + jjc] > 0.f);
        ml[tid] = ok ? 0.f : -1e9f;
    }
    __syncthreads();

    const int chalf = tid & 1;
    const int h     = (tid >> 1) & 3;
    const int jloc  = tid >> 3;
    const int j     = j0 + jloc;
    const int c0l   = chalf * 16;
    const size_t base = ((size_t)i*N + j)*CZ + h*CH + c0l;

    float qv[16];
    {
        uint4 q1 = *(const uint4*)(q + base);
        uint4 q2 = *(const uint4*)(q + base + 8);
        const ushort* s1 = (const ushort*)&q1;
        const ushort* s2 = (const ushort*)&q2;
        #pragma unroll
        for (int t=0; t<8; t++) { qv[t] = bf2f(s1[t]); qv[8+t] = bf2f(s2[t]); }
    }

    const float scale = 0.17677669529663688f; // 1/sqrt(32)
    float lg[WIN];
    #pragma unroll
    for (int w=0; w<WIN; w++) {
        const int rel = jloc + w;
        float dot = 0.f;
        #pragma unroll
        for (int c4=0; c4<4; c4++) {
            float4 kv = *(const float4*)&kl[rel][h][c0l + c4*4];
            dot += qv[c4*4+0]*kv.x + qv[c4*4+1]*kv.y + qv[c4*4+2]*kv.z + qv[c4*4+3]*kv.w;
        }
        dot += __shfl_xor(dot, 1);
        const int jj  = j - 8 + w;
        const int jjc = min(max(jj, 0), N-1);
        lg[w] = dot*scale + tb[((size_t)j*N + jjc)*4 + h] + ml[rel];
    }
    float mx = lg[0];
    #pragma unroll
    for (int w=1; w<WIN; w++) mx = fmaxf(mx, lg[w]);
    float sum = 0.f;
    #pragma unroll
    for (int w=0; w<WIN; w++) { lg[w] = __expf(lg[w]-mx); sum += lg[w]; }
    const float inv = 1.f/sum;

    float o[16];
    #pragma unroll
    for (int c=0; c<16; c++) o[c] = 0.f;
    #pragma unroll
    for (int w=0; w<WIN; w++) {
        const float p   = lg[w]*inv;
        const int   rel = jloc + w;
        #pragma unroll
        for (int c4=0; c4<4; c4++) {
            float4 vv = *(const float4*)&vl[rel][h][c0l + c4*4];
            o[c4*4+0] += p*vv.x; o[c4*4+1] += p*vv.y;
            o[c4*4+2] += p*vv.z; o[c4*4+3] += p*vv.w;
        }
    }

    uint4 o1, o2;
    {
        uint4 g1 = *(const uint4*)(g + base);
        uint4 g2 = *(const uint4*)(g + base + 8);
        const ushort* s1 = (const ushort*)&g1;
        const ushort* s2 = (const ushort*)&g2;
        ushort* p1 = (ushort*)&o1; ushort* p2 = (ushort*)&o2;
        #pragma unroll
        for (int t=0; t<8; t++) {
            p1[t] = f2bf(o[t]   * bf2f(s1[t]));
            p2[t] = f2bf(o[8+t] * bf2f(s2[t]));
        }
    }
    __syncthreads();                 // all kl/vl reads done -> safe to overwrite with po
    *(uint4*)&po[jloc][h*CH + c0l]     = o1;
    *(uint4*)&po[jloc][h*CH + c0l + 8] = o2;

    // ---- out-GEMM: wave owns cols [wid*32, wid*32+32) ----
    const int wid = tid >> 6, lane = tid & 63;
    const int l16 = lane & 15, lk = lane >> 4;
    bf16x8 bfrag[2][4];
    float4 bo4[2];
    #pragma unroll
    for (int nt2=0; nt2<2; nt2++) {
        const int col = wid*32 + nt2*16 + l16;
        #pragma unroll
        for (int ks=0; ks<4; ks++) {
            ushort tmp[8];
            #pragma unroll
            for (int t=0; t<8; t++)
                tmp[t] = f2bf(wout[(size_t)(ks*32 + lk*8 + t)*CZ + col]);
            bfrag[nt2][ks] = *(const bf16x8*)tmp;
        }
        bo4[nt2] = *(const float4*)(bout + wid*32 + nt2*16 + lk*4);
    }
    __syncthreads();

    #pragma unroll
    for (int rt=0; rt<2; rt++) {
        bf16x8 af[4];
        #pragma unroll
        for (int ks=0; ks<4; ks++)
            af[ks] = *(const bf16x8*)&po[rt*16 + l16][ks*32 + lk*8];
        const size_t orow = (size_t)(i*N + j0 + rt*16 + l16)*CZ;
        #pragma unroll
        for (int nt2=0; nt2<2; nt2++) {
            f32x4 acc = {0.f,0.f,0.f,0.f};
            #pragma unroll
            for (int ks=0; ks<4; ks++)   // swapped -> C^T: row=l16, 4 consecutive cols
                acc = __builtin_amdgcn_mfma_f32_16x16x32_bf16(bfrag[nt2][ks], af[ks], acc, 0, 0, 0);
            float4 ov;
            ov.x = acc[0] + bo4[nt2].x; ov.y = acc[1] + bo4[nt2].y;
            ov.z = acc[2] + bo4[nt2].z; ov.w = acc[3] + bo4[nt2].w;
            *(float4*)(out + orow + wid*32 + nt2*16 + lk*4) = ov;
        }
    }
}

extern "C" void kernel_launch(void* const* d_in, const int* in_sizes, int n_in,
                              void* d_out, int out_size, void* d_ws, size_t ws_size,
                              hipStream_t stream)
{
    const float* z    = (const float*)d_in[0];
    const float* mask = (const float*)d_in[1];
    const float* lnw  = (const float*)d_in[2];
    const float* lnb  = (const float*)d_in[3];
    const float* wq   = (const float*)d_in[4];
    const float* wk   = (const float*)d_in[5];
    const float* wv   = (const float*)d_in[6];
    const float* wb   = (const float*)d_in[7];
    const float* wg   = (const float*)d_in[8];
    const float* bg   = (const float*)d_in[9];
    const float* wo   = (const float*)d_in[10];
    const float* bo   = (const float*)d_in[11];

    const size_t NE = (size_t)NROWS*CZ;
    ushort* zl = (ushort*)d_ws;          // bf16 [NROWS][128]
    ushort* q  = zl + NE;
    ushort* k  = q + NE;
    ushort* v  = k + NE;
    ushort* g  = v + NE;
    float*  tb = (float*)(g + NE);       // f32 [NROWS][4]
    if (ws_size < 5*NE*sizeof(ushort) + (size_t)NROWS*4*sizeof(float)) return;

    k_ln  <<<NROWS/16, 256, 0, stream>>>(z, lnw, lnb, wb, zl, tb);
    k_gemm<<<4*(NROWS/128), 256, 0, stream>>>(zl, wq, wk, wv, wg, bg, q, k, v, g);
    k_attn_out<<<dim3(N/32, N), 256, 0, stream>>>(q, k, v, g, tb, mask, wo, bo, (float*)d_out);
}

// Round 14
// 60.391 us; speedup vs baseline: 1.2516x; 1.2055x over previous
//
#include <hip/hip_runtime.h>
#include <hip/hip_bf16.h>

#define N 192
#define CZ 128
#define NH 4
#define CH 32
#define WIN 16
#define NROWS (N*N)   // 36864
#define RPB 144       // rows per k_proj block: 256 blocks exactly, zero dispatch tail

typedef __attribute__((ext_vector_type(8))) short bf16x8;
typedef __attribute__((ext_vector_type(4))) float f32x4;

static __device__ __forceinline__ ushort f2bf(float x){
    union{float f; unsigned u;} a; a.f = x;
    unsigned r = a.u + 0x7fffu + ((a.u>>16)&1u);   // RNE
    return (ushort)(r>>16);
}
static __device__ __forceinline__ float bf2f(ushort s){
    union{unsigned u; float f;} a; a.u = ((unsigned)s)<<16;
    return a.f;
}

// ---------------- K1: LN (-> LDS) + q/k/v/g MFMA projections + tb ----------------
// Block = 144 rows, 4 waves, grid = 256 (one block per CU, no tail round).
// zl lives only in LDS. B-frags in registers. C^T MFMA + per-wave LDS repack
// -> full 64B-sector stores. LN z-loads depth-2 pipelined.
__global__ __launch_bounds__(256, 4) void k_proj(
    const float* __restrict__ z, const float* __restrict__ lnw, const float* __restrict__ lnb,
    const float* __restrict__ wbias,
    const float* __restrict__ wq, const float* __restrict__ wk,
    const float* __restrict__ wv, const float* __restrict__ wg,
    const float* __restrict__ bg,
    ushort* __restrict__ q, ushort* __restrict__ k,
    ushort* __restrict__ v, ushort* __restrict__ g, float* __restrict__ tb)
{
    __shared__ ushort zlds[RPB][132];   // +4 pad: 264B row stride -> even LDS banks
    __shared__ ushort st[4][16][36];    // per-wave store-repack scratch
    const int rbase = blockIdx.x * RPB;
    const int tid  = threadIdx.x;
    const int wid  = tid >> 6, lane = tid & 63;
    const int l16  = lane & 15, lk = lane >> 4;

    // ---- LN phase: 9 x 16 rows, z-loads depth-2 pipelined ----
    {
        const float* zr0 = z + (size_t)(rbase + wid*4 + lk)*CZ + l16*8;
        float4 a = ((const float4*)zr0)[0];
        float4 b = ((const float4*)zr0)[1];
        for (int it = 0; it < 9; ++it) {
            float4 na, nb;
            if (it < 8) {
                const float* zr = z + (size_t)(rbase + (it+1)*16 + wid*4 + lk)*CZ + l16*8;
                na = ((const float4*)zr)[0];
                nb = ((const float4*)zr)[1];
            }
            const int r = it*16 + wid*4 + lk;
            float s  = a.x+a.y+a.z+a.w + b.x+b.y+b.z+b.w;
            float s2 = a.x*a.x+a.y*a.y+a.z*a.z+a.w*a.w + b.x*b.x+b.y*b.y+b.z*b.z+b.w*b.w;
            #pragma unroll
            for (int off=1; off<16; off<<=1) { s += __shfl_xor(s, off); s2 += __shfl_xor(s2, off); }
            const float mu   = s * (1.f/CZ);
            const float rstd = rsqrtf(s2*(1.f/CZ) - mu*mu + 1e-5f);
            const int c0 = l16*8;
            float vals[8] = {a.x,a.y,a.z,a.w,b.x,b.y,b.z,b.w};
            float tbp[4] = {0.f,0.f,0.f,0.f};
            uint4 pk; ushort* ph = (ushort*)&pk;
            #pragma unroll
            for (int t=0; t<8; t++) {
                const float nv = (vals[t]-mu)*rstd*lnw[c0+t] + lnb[c0+t];
                ph[t] = f2bf(nv);
                float4 wb4 = *(const float4*)(wbias + (c0+t)*4);
                tbp[0] += nv*wb4.x; tbp[1] += nv*wb4.y;
                tbp[2] += nv*wb4.z; tbp[3] += nv*wb4.w;
            }
            *(uint4*)&zlds[r][c0] = pk;
            #pragma unroll
            for (int off=1; off<16; off<<=1) {
                #pragma unroll
                for (int h=0; h<4; h++) tbp[h] += __shfl_xor(tbp[h], off);
            }
            if (l16 == 0) *(float4*)(tb + (size_t)(rbase+r)*4) = make_float4(tbp[0],tbp[1],tbp[2],tbp[3]);
            a = na; b = nb;
        }
    }
    __syncthreads();

    // ---- projection phase: 4 matrices, wave owns cols [wid*32, wid*32+32) ----
    for (int m = 0; m < 4; ++m) {
        const float* W = (m==0)?wq:(m==1)?wk:(m==2)?wv:wg;
        ushort*      O = (m==0)?q :(m==1)?k :(m==2)?v :g;

        bf16x8 bfrag[2][4];
        float4 bg4[2];
        #pragma unroll
        for (int nt2=0; nt2<2; nt2++) {
            const int col = wid*32 + nt2*16 + l16;
            #pragma unroll
            for (int ks=0; ks<4; ks++) {
                ushort tmp[8];
                #pragma unroll
                for (int i=0; i<8; i++)
                    tmp[i] = f2bf(W[(size_t)(ks*32 + lk*8 + i)*CZ + col]);
                bfrag[nt2][ks] = *(const bf16x8*)tmp;
            }
            if (m == 3) bg4[nt2] = *(const float4*)(bg + wid*32 + nt2*16 + lk*4);
        }

        #pragma unroll 1
        for (int rt=0; rt<9; rt++) {
            bf16x8 af[4];
            #pragma unroll
            for (int ks=0; ks<4; ks++)
                af[ks] = *(const bf16x8*)&zlds[rt*16 + l16][ks*32 + lk*8];
            #pragma unroll
            for (int nt2=0; nt2<2; nt2++) {
                f32x4 acc = {0.f,0.f,0.f,0.f};
                #pragma unroll
                for (int ks=0; ks<4; ks++)   // swapped args -> C^T fragment layout
                    acc = __builtin_amdgcn_mfma_f32_16x16x32_bf16(bfrag[nt2][ks], af[ks], acc, 0, 0, 0);
                float v0,v1,v2,v3;
                if (m == 3) {
                    v0 = 1.f/(1.f + __expf(-(acc[0] + bg4[nt2].x)));
                    v1 = 1.f/(1.f + __expf(-(acc[1] + bg4[nt2].y)));
                    v2 = 1.f/(1.f + __expf(-(acc[2] + bg4[nt2].z)));
                    v3 = 1.f/(1.f + __expf(-(acc[3] + bg4[nt2].w)));
                } else { v0=acc[0]; v1=acc[1]; v2=acc[2]; v3=acc[3]; }
                uint2 pk2;
                pk2.x = (unsigned)f2bf(v0) | ((unsigned)f2bf(v1)<<16);
                pk2.y = (unsigned)f2bf(v2) | ((unsigned)f2bf(v3)<<16);
                *(uint2*)&st[wid][l16][nt2*16 + lk*4] = pk2;
            }
            // readback: 4 lanes x 16B = full 64B sector per row (in-wave DS ordering)
            const int row = lane >> 2, c8 = lane & 3;
            uint4 ov = *(const uint4*)&st[wid][row][c8*8];
            *(uint4*)(O + (size_t)(rbase + rt*16 + row)*CZ + wid*32 + c8*8) = ov;
        }
    }
}

// ---------------- K2: windowed attention + gate + out-GEMM fused ----------------
__global__ __launch_bounds__(256, 3) void k_attn_out(
    const ushort* __restrict__ q, const ushort* __restrict__ k, const ushort* __restrict__ v,
    const ushort* __restrict__ g, const float* __restrict__ tb, const float* __restrict__ mask,
    const float* __restrict__ wout, const float* __restrict__ bout, float* __restrict__ out)
{
    __shared__ float kl[47][NH][33];
    __shared__ float vl[47][NH][33];
    __shared__ float ml[47];
    ushort (*po)[132] = (ushort (*)[132])&kl[0][0][0];   // aliases kl after barrier

    const int i   = blockIdx.y;
    const int j0  = blockIdx.x * 32;
    const int tid = threadIdx.x;

    for (int idx = tid; idx < 47*16; idx += 256) {
        const int row = idx >> 4, c8 = idx & 15;
        const int jj  = j0 - 8 + row;
        const int jjc = min(max(jj, 0), N-1);
        const size_t goff = ((size_t)i*N + jjc)*CZ + c8*8;
        uint4 ku = *(const uint4*)(k + goff);
        uint4 vu = *(const uint4*)(v + goff);
        const int hh = c8 >> 2, co = (c8 & 3)*8;
        const ushort* ks_ = (const ushort*)&ku;
        const ushort* vs_ = (const ushort*)&vu;
        #pragma unroll
        for (int t=0; t<8; t++) {
            kl[row][hh][co+t] = bf2f(ks_[t]);
            vl[row][hh][co+t] = bf2f(vs_[t]);
        }
    }
    if (tid < 47) {
        const int jj  = j0 - 8 + tid;
        const int jjc = min(max(jj, 0), N-1);
        const bool ok = (jj >= 0) && (jj < N) && (mask[(size_t)i*N + jjc] > 0.f);
        ml[tid] = ok ? 0.f : -1e9f;
    }
    __syncthreads();

    const int chalf = tid & 1;
    const int h     = (tid >> 1) & 3;
    const int jloc  = tid >> 3;
    const int j     = j0 + jloc;
    const int c0l   = chalf * 16;
    const size_t base = ((size_t)i*N + j)*CZ + h*CH + c0l;

    float qv[16];
    {
        uint4 q1 = *(const uint4*)(q + base);
        uint4 q2 = *(const uint4*)(q + base + 8);
        const ushort* s1 = (const ushort*)&q1;
        const ushort* s2 = (const ushort*)&q2;
        #pragma unroll
        for (int t=0; t<8; t++) { qv[t] = bf2f(s1[t]); qv[8+t] = bf2f(s2[t]); }
    }

    const float scale = 0.17677669529663688f; // 1/sqrt(32)
    float lg[WIN];
    #pragma unroll
    for (int w=0; w<WIN; w++) {
        const int rel = jloc + w;
        float dot = 0.f;
        #pragma unroll
        for (int c4=0; c4<4; c4++) {
            float4 kv = *(const float4*)&kl[rel][h][c0l + c4*4];
            dot += qv[c4*4+0]*kv.x + qv[c4*4+1]*kv.y + qv[c4*4+2]*kv.z + qv[c4*4+3]*kv.w;
        }
        dot += __shfl_xor(dot, 1);
        const int jj  = j - 8 + w;
        const int jjc = min(max(jj, 0), N-1);
        lg[w] = dot*scale + tb[((size_t)j*N + jjc)*4 + h] + ml[rel];
    }
    float mx = lg[0];
    #pragma unroll
    for (int w=1; w<WIN; w++) mx = fmaxf(mx, lg[w]);
    float sum = 0.f;
    #pragma unroll
    for (int w=0; w<WIN; w++) { lg[w] = __expf(lg[w]-mx); sum += lg[w]; }
    const float inv = 1.f/sum;

    float o[16];
    #pragma unroll
    for (int c=0; c<16; c++) o[c] = 0.f;
    #pragma unroll
    for (int w=0; w<WIN; w++) {
        const float p   = lg[w]*inv;
        const int   rel = jloc + w;
        #pragma unroll
        for (int c4=0; c4<4; c4++) {
            float4 vv = *(const float4*)&vl[rel][h][c0l + c4*4];
            o[c4*4+0] += p*vv.x; o[c4*4+1] += p*vv.y;
            o[c4*4+2] += p*vv.z; o[c4*4+3] += p*vv.w;
        }
    }

    uint4 o1, o2;
    {
        uint4 g1 = *(const uint4*)(g + base);
        uint4 g2 = *(const uint4*)(g + base + 8);
        const ushort* s1 = (const ushort*)&g1;
        const ushort* s2 = (const ushort*)&g2;
        ushort* p1 = (ushort*)&o1; ushort* p2 = (ushort*)&o2;
        #pragma unroll
        for (int t=0; t<8; t++) {
            p1[t] = f2bf(o[t]   * bf2f(s1[t]));
            p2[t] = f2bf(o[8+t] * bf2f(s2[t]));
        }
    }
    __syncthreads();                 // all kl/vl reads done -> safe to overwrite with po
    *(uint4*)&po[jloc][h*CH + c0l]     = o1;
    *(uint4*)&po[jloc][h*CH + c0l + 8] = o2;

    // ---- out-GEMM: wave owns cols [wid*32, wid*32+32) ----
    const int wid = tid >> 6, lane = tid & 63;
    const int l16 = lane & 15, lk = lane >> 4;
    bf16x8 bfrag[2][4];
    float4 bo4[2];
    #pragma unroll
    for (int nt2=0; nt2<2; nt2++) {
        const int col = wid*32 + nt2*16 + l16;
        #pragma unroll
        for (int ks=0; ks<4; ks++) {
            ushort tmp[8];
            #pragma unroll
            for (int t=0; t<8; t++)
                tmp[t] = f2bf(wout[(size_t)(ks*32 + lk*8 + t)*CZ + col]);
            bfrag[nt2][ks] = *(const bf16x8*)tmp;
        }
        bo4[nt2] = *(const float4*)(bout + wid*32 + nt2*16 + lk*4);
    }
    __syncthreads();

    #pragma unroll
    for (int rt=0; rt<2; rt++) {
        bf16x8 af[4];
        #pragma unroll
        for (int ks=0; ks<4; ks++)
            af[ks] = *(const bf16x8*)&po[rt*16 + l16][ks*32 + lk*8];
        const size_t orow = (size_t)(i*N + j0 + rt*16 + l16)*CZ;
        #pragma unroll
        for (int nt2=0; nt2<2; nt2++) {
            f32x4 acc = {0.f,0.f,0.f,0.f};
            #pragma unroll
            for (int ks=0; ks<4; ks++)   // swapped -> C^T: row=l16, 4 consecutive cols
                acc = __builtin_amdgcn_mfma_f32_16x16x32_bf16(bfrag[nt2][ks], af[ks], acc, 0, 0, 0);
            float4 ov;
            ov.x = acc[0] + bo4[nt2].x; ov.y = acc[1] + bo4[nt2].y;
            ov.z = acc[2] + bo4[nt2].z; ov.w = acc[3] + bo4[nt2].w;
            *(float4*)(out + orow + wid*32 + nt2*16 + lk*4) = ov;
        }
    }
}

extern "C" void kernel_launch(void* const* d_in, const int* in_sizes, int n_in,
                              void* d_out, int out_size, void* d_ws, size_t ws_size,
                              hipStream_t stream)
{
    const float* z    = (const float*)d_in[0];
    const float* mask = (const float*)d_in[1];
    const float* lnw  = (const float*)d_in[2];
    const float* lnb  = (const float*)d_in[3];
    const float* wq   = (const float*)d_in[4];
    const float* wk   = (const float*)d_in[5];
    const float* wv   = (const float*)d_in[6];
    const float* wb   = (const float*)d_in[7];
    const float* wg   = (const float*)d_in[8];
    const float* bg   = (const float*)d_in[9];
    const float* wo   = (const float*)d_in[10];
    const float* bo   = (const float*)d_in[11];

    const size_t NE = (size_t)NROWS*CZ;
    ushort* q  = (ushort*)d_ws;
    ushort* k  = q + NE;
    ushort* v  = k + NE;
    ushort* g  = v + NE;
    float*  tb = (float*)(g + NE);       // f32 [NROWS][4]
    if (ws_size < 4*NE*sizeof(ushort) + (size_t)NROWS*4*sizeof(float)) return;

    k_proj<<<NROWS/RPB, 256, 0, stream>>>(z, lnw, lnb, wb, wq, wk, wv, wg, bg, q, k, v, g, tb);
    k_attn_out<<<dim3(N/32, N), 256, 0, stream>>>(q, k, v, g, tb, mask, wo, bo, (float*)d_out);
}

// Round 15
// 56.359 us; speedup vs baseline: 1.3411x; 1.0715x over previous
//
#include <hip/hip_runtime.h>
#include <hip/hip_bf16.h>

#define N 192
#define CZ 128
#define NH 4
#define CH 32
#define WIN 16
#define NROWS (N*N)   // 36864
#define RPB 144       // rows per k_proj block: 256 blocks exactly, zero dispatch tail

typedef __attribute__((ext_vector_type(8))) short bf16x8;
typedef __attribute__((ext_vector_type(4))) float f32x4;

static __device__ __forceinline__ ushort f2bf(float x){
    union{float f; unsigned u;} a; a.f = x;
    unsigned r = a.u + 0x7fffu + ((a.u>>16)&1u);   // RNE
    return (ushort)(r>>16);
}
static __device__ __forceinline__ float bf2f(ushort s){
    union{unsigned u; float f;} a; a.u = ((unsigned)s)<<16;
    return a.f;
}

// ---------------- K0: pack 5 weight matrices into bf16 MFMA-fragment order ----------------
// WP[m][nt*2048 + ks*512 + lane*8 + i] = bf16(W[(ks*32 + (lane>>4)*8 + i)*128 + nt*16 + (lane&15)])
// -> in-kernel fragment load = ONE coalesced b128 per (nt,ks): WP + nt*2048 + ks*512 + lane*8
__global__ __launch_bounds__(256) void k_pack(
    const float* __restrict__ wq, const float* __restrict__ wk,
    const float* __restrict__ wv, const float* __restrict__ wg,
    const float* __restrict__ wo, ushort* __restrict__ WP)
{
    const int m = blockIdx.y;
    const float* W = (m==0)?wq:(m==1)?wk:(m==2)?wv:(m==3)?wg:wo;
    const int f = blockIdx.x*256 + threadIdx.x;     // fragment index 0..2047
    const int nt = f >> 8, ks = (f >> 6) & 3, lane8 = f & 63;
    const int col = nt*16 + (lane8 & 15);
    const int r0  = ks*32 + (lane8 >> 4)*8;
    ushort tmp[8];
    #pragma unroll
    for (int i=0; i<8; i++) tmp[i] = f2bf(W[(size_t)(r0+i)*CZ + col]);
    *(uint4*)(WP + (size_t)m*16384 + (size_t)f*8) = *(uint4*)tmp;
}

// ---------------- K1: LN (-> LDS) + q/k/v/g MFMA projections + tb ----------------
// Block = 144 rows, 4 waves, grid = 256 (one block per CU, no tail round).
__global__ __launch_bounds__(256, 4) void k_proj(
    const float* __restrict__ z, const float* __restrict__ lnw, const float* __restrict__ lnb,
    const float* __restrict__ wbias, const ushort* __restrict__ WP,
    const float* __restrict__ bg,
    ushort* __restrict__ q, ushort* __restrict__ k,
    ushort* __restrict__ v, ushort* __restrict__ g, float* __restrict__ tb)
{
    __shared__ ushort zlds[RPB][132];   // +4 pad: 264B row stride
    __shared__ ushort st[4][16][36];    // per-wave store-repack scratch
    const int rbase = blockIdx.x * RPB;
    const int tid  = threadIdx.x;
    const int wid  = tid >> 6, lane = tid & 63;
    const int l16  = lane & 15, lk = lane >> 4;

    // ---- LN phase: 9 x 16 rows, z-loads depth-2 pipelined ----
    {
        const float* zr0 = z + (size_t)(rbase + wid*4 + lk)*CZ + l16*8;
        float4 a = ((const float4*)zr0)[0];
        float4 b = ((const float4*)zr0)[1];
        for (int it = 0; it < 9; ++it) {
            float4 na, nb;
            if (it < 8) {
                const float* zr = z + (size_t)(rbase + (it+1)*16 + wid*4 + lk)*CZ + l16*8;
                na = ((const float4*)zr)[0];
                nb = ((const float4*)zr)[1];
            }
            const int r = it*16 + wid*4 + lk;
            float s  = a.x+a.y+a.z+a.w + b.x+b.y+b.z+b.w;
            float s2 = a.x*a.x+a.y*a.y+a.z*a.z+a.w*a.w + b.x*b.x+b.y*b.y+b.z*b.z+b.w*b.w;
            #pragma unroll
            for (int off=1; off<16; off<<=1) { s += __shfl_xor(s, off); s2 += __shfl_xor(s2, off); }
            const float mu   = s * (1.f/CZ);
            const float rstd = rsqrtf(s2*(1.f/CZ) - mu*mu + 1e-5f);
            const int c0 = l16*8;
            float vals[8] = {a.x,a.y,a.z,a.w,b.x,b.y,b.z,b.w};
            float tbp[4] = {0.f,0.f,0.f,0.f};
            uint4 pk; ushort* ph = (ushort*)&pk;
            #pragma unroll
            for (int t=0; t<8; t++) {
                const float nv = (vals[t]-mu)*rstd*lnw[c0+t] + lnb[c0+t];
                ph[t] = f2bf(nv);
                float4 wb4 = *(const float4*)(wbias + (c0+t)*4);
                tbp[0] += nv*wb4.x; tbp[1] += nv*wb4.y;
                tbp[2] += nv*wb4.z; tbp[3] += nv*wb4.w;
            }
            *(uint4*)&zlds[r][c0] = pk;
            #pragma unroll
            for (int off=1; off<16; off<<=1) {
                #pragma unroll
                for (int h=0; h<4; h++) tbp[h] += __shfl_xor(tbp[h], off);
            }
            if (l16 == 0) *(float4*)(tb + (size_t)(rbase+r)*4) = make_float4(tbp[0],tbp[1],tbp[2],tbp[3]);
            a = na; b = nb;
        }
    }
    __syncthreads();

    // ---- projection phase: 4 matrices, wave owns cols [wid*32, wid*32+32) ----
    for (int m = 0; m < 4; ++m) {
        const ushort* WPm = WP + (size_t)m*16384;
        ushort* O = (m==0)?q:(m==1)?k:(m==2)?v:g;

        bf16x8 bfrag[2][4];
        float4 bg4[2];
        #pragma unroll
        for (int nt2=0; nt2<2; nt2++) {
            const int nt = wid*2 + nt2;
            #pragma unroll
            for (int ks=0; ks<4; ks++)
                bfrag[nt2][ks] = *(const bf16x8*)(WPm + nt*2048 + ks*512 + lane*8);
            if (m == 3) bg4[nt2] = *(const float4*)(bg + wid*32 + nt2*16 + lk*4);
        }

        #pragma unroll 1
        for (int rt=0; rt<9; rt++) {
            bf16x8 af[4];
            #pragma unroll
            for (int ks=0; ks<4; ks++)
                af[ks] = *(const bf16x8*)&zlds[rt*16 + l16][ks*32 + lk*8];
            #pragma unroll
            for (int nt2=0; nt2<2; nt2++) {
                f32x4 acc = {0.f,0.f,0.f,0.f};
                #pragma unroll
                for (int ks=0; ks<4; ks++)   // swapped args -> C^T fragment layout
                    acc = __builtin_amdgcn_mfma_f32_16x16x32_bf16(bfrag[nt2][ks], af[ks], acc, 0, 0, 0);
                float v0,v1,v2,v3;
                if (m == 3) {
                    v0 = 1.f/(1.f + __expf(-(acc[0] + bg4[nt2].x)));
                    v1 = 1.f/(1.f + __expf(-(acc[1] + bg4[nt2].y)));
                    v2 = 1.f/(1.f + __expf(-(acc[2] + bg4[nt2].z)));
                    v3 = 1.f/(1.f + __expf(-(acc[3] + bg4[nt2].w)));
                } else { v0=acc[0]; v1=acc[1]; v2=acc[2]; v3=acc[3]; }
                uint2 pk2;
                pk2.x = (unsigned)f2bf(v0) | ((unsigned)f2bf(v1)<<16);
                pk2.y = (unsigned)f2bf(v2) | ((unsigned)f2bf(v3)<<16);
                *(uint2*)&st[wid][l16][nt2*16 + lk*4] = pk2;
            }
            // readback: 4 lanes x 16B = full 64B sector per row (in-wave DS ordering)
            const int row = lane >> 2, c8 = lane & 3;
            uint4 ov = *(const uint4*)&st[wid][row][c8*8];
            *(uint4*)(O + (size_t)(rbase + rt*16 + row)*CZ + wid*32 + c8*8) = ov;
        }
    }
}

// ---------------- K2: windowed attention + gate + out-GEMM (bf16 K/V LDS) ----------------
__global__ __launch_bounds__(256, 4) void k_attn_out(
    const ushort* __restrict__ q, const ushort* __restrict__ k, const ushort* __restrict__ v,
    const ushort* __restrict__ g, const float* __restrict__ tb, const float* __restrict__ mask,
    const ushort* __restrict__ WPo, const float* __restrict__ bout, float* __restrict__ out)
{
    __shared__ ushort kl[47][NH][40];   // bf16, 40-pad: 16B-aligned rows, uniform banks
    __shared__ ushort vl[47][NH][40];
    __shared__ float  ml[47];
    ushort (*po)[136] = (ushort (*)[136])&kl[0][0][0];   // aliases kl after barrier (8.7KB<=15KB)

    const int i   = blockIdx.y;
    const int j0  = blockIdx.x * 32;
    const int tid = threadIdx.x;

    // stage K/V window: pure uint4 copies, no conversion
    for (int idx = tid; idx < 47*16; idx += 256) {
        const int row = idx >> 4, c8 = idx & 15;
        const int jj  = j0 - 8 + row;
        const int jjc = min(max(jj, 0), N-1);
        const size_t goff = ((size_t)i*N + jjc)*CZ + c8*8;
        const int hh = c8 >> 2, co = (c8 & 3)*8;
        *(uint4*)&kl[row][hh][co] = *(const uint4*)(k + goff);
        *(uint4*)&vl[row][hh][co] = *(const uint4*)(v + goff);
    }
    if (tid < 47) {
        const int jj  = j0 - 8 + tid;
        const int jjc = min(max(jj, 0), N-1);
        const bool ok = (jj >= 0) && (jj < N) && (mask[(size_t)i*N + jjc] > 0.f);
        ml[tid] = ok ? 0.f : -1e9f;
    }
    __syncthreads();

    const int chalf = tid & 1;
    const int h     = (tid >> 1) & 3;
    const int jloc  = tid >> 3;
    const int j     = j0 + jloc;
    const int c0l   = chalf * 16;
    const size_t base = ((size_t)i*N + j)*CZ + h*CH + c0l;

    float qv[16];
    {
        uint4 q1 = *(const uint4*)(q + base);
        uint4 q2 = *(const uint4*)(q + base + 8);
        const ushort* s1 = (const ushort*)&q1;
        const ushort* s2 = (const ushort*)&q2;
        #pragma unroll
        for (int t=0; t<8; t++) { qv[t] = bf2f(s1[t]); qv[8+t] = bf2f(s2[t]); }
    }

    const float scale = 0.17677669529663688f; // 1/sqrt(32)
    float lg[WIN];
    #pragma unroll
    for (int w=0; w<WIN; w++) {
        const int rel = jloc + w;
        float dot = 0.f;
        #pragma unroll
        for (int c4=0; c4<2; c4++) {
            uint4 kv = *(const uint4*)&kl[rel][h][c0l + c4*8];
            const ushort* kp = (const ushort*)&kv;
            #pragma unroll
            for (int t=0; t<8; t++) dot += qv[c4*8+t]*bf2f(kp[t]);
        }
        dot += __shfl_xor(dot, 1);
        const int jj  = j - 8 + w;
        const int jjc = min(max(jj, 0), N-1);
        lg[w] = dot*scale + tb[((size_t)j*N + jjc)*4 + h] + ml[rel];
    }
    float mx = lg[0];
    #pragma unroll
    for (int w=1; w<WIN; w++) mx = fmaxf(mx, lg[w]);
    float sum = 0.f;
    #pragma unroll
    for (int w=0; w<WIN; w++) { lg[w] = __expf(lg[w]-mx); sum += lg[w]; }
    const float inv = 1.f/sum;

    float o[16];
    #pragma unroll
    for (int c=0; c<16; c++) o[c] = 0.f;
    #pragma unroll
    for (int w=0; w<WIN; w++) {
        const float p   = lg[w]*inv;
        const int   rel = jloc + w;
        #pragma unroll
        for (int c4=0; c4<2; c4++) {
            uint4 vv = *(const uint4*)&vl[rel][h][c0l + c4*8];
            const ushort* vp = (const ushort*)&vv;
            #pragma unroll
            for (int t=0; t<8; t++) o[c4*8+t] += p*bf2f(vp[t]);
        }
    }

    uint4 o1, o2;
    {
        uint4 g1 = *(const uint4*)(g + base);
        uint4 g2 = *(const uint4*)(g + base + 8);
        const ushort* s1 = (const ushort*)&g1;
        const ushort* s2 = (const ushort*)&g2;
        ushort* p1 = (ushort*)&o1; ushort* p2 = (ushort*)&o2;
        #pragma unroll
        for (int t=0; t<8; t++) {
            p1[t] = f2bf(o[t]   * bf2f(s1[t]));
            p2[t] = f2bf(o[8+t] * bf2f(s2[t]));
        }
    }
    __syncthreads();                 // all kl/vl reads done -> safe to overwrite with po
    *(uint4*)&po[jloc][h*CH + c0l]     = o1;
    *(uint4*)&po[jloc][h*CH + c0l + 8] = o2;

    // ---- out-GEMM: wave owns cols [wid*32, wid*32+32), packed-B loads ----
    const int wid = tid >> 6, lane = tid & 63;
    const int l16 = lane & 15, lk = lane >> 4;
    bf16x8 bfrag[2][4];
    float4 bo4[2];
    #pragma unroll
    for (int nt2=0; nt2<2; nt2++) {
        const int nt = wid*2 + nt2;
        #pragma unroll
        for (int ks=0; ks<4; ks++)
            bfrag[nt2][ks] = *(const bf16x8*)(WPo + nt*2048 + ks*512 + lane*8);
        bo4[nt2] = *(const float4*)(bout + wid*32 + nt2*16 + lk*4);
    }
    __syncthreads();

    #pragma unroll
    for (int rt=0; rt<2; rt++) {
        bf16x8 af[4];
        #pragma unroll
        for (int ks=0; ks<4; ks++)
            af[ks] = *(const bf16x8*)&po[rt*16 + l16][ks*32 + lk*8];
        const size_t orow = (size_t)(i*N + j0 + rt*16 + l16)*CZ;
        #pragma unroll
        for (int nt2=0; nt2<2; nt2++) {
            f32x4 acc = {0.f,0.f,0.f,0.f};
            #pragma unroll
            for (int ks=0; ks<4; ks++)   // swapped -> C^T: row=l16, 4 consecutive cols
                acc = __builtin_amdgcn_mfma_f32_16x16x32_bf16(bfrag[nt2][ks], af[ks], acc, 0, 0, 0);
            float4 ov;
            ov.x = acc[0] + bo4[nt2].x; ov.y = acc[1] + bo4[nt2].y;
            ov.z = acc[2] + bo4[nt2].z; ov.w = acc[3] + bo4[nt2].w;
            *(float4*)(out + orow + wid*32 + nt2*16 + lk*4) = ov;
        }
    }
}

extern "C" void kernel_launch(void* const* d_in, const int* in_sizes, int n_in,
                              void* d_out, int out_size, void* d_ws, size_t ws_size,
                              hipStream_t stream)
{
    const float* z    = (const float*)d_in[0];
    const float* mask = (const float*)d_in[1];
    const float* lnw  = (const float*)d_in[2];
    const float* lnb  = (const float*)d_in[3];
    const float* wq   = (const float*)d_in[4];
    const float* wk   = (const float*)d_in[5];
    const float* wv   = (const float*)d_in[6];
    const float* wb   = (const float*)d_in[7];
    const float* wg   = (const float*)d_in[8];
    const float* bg   = (const float*)d_in[9];
    const float* wo   = (const float*)d_in[10];
    const float* bo   = (const float*)d_in[11];

    const size_t NE = (size_t)NROWS*CZ;
    ushort* q  = (ushort*)d_ws;
    ushort* k  = q + NE;
    ushort* v  = k + NE;
    ushort* g  = v + NE;
    float*  tb = (float*)(g + NE);             // f32 [NROWS][4]
    ushort* WP = (ushort*)(tb + (size_t)NROWS*4);  // 5 x 16384 bf16, fragment-ordered
    if (ws_size < 4*NE*sizeof(ushort) + (size_t)NROWS*4*sizeof(float) + 5*16384*sizeof(ushort)) return;

    k_pack<<<dim3(8,5), 256, 0, stream>>>(wq, wk, wv, wg, wo, WP);
    k_proj<<<NROWS/RPB, 256, 0, stream>>>(z, lnw, lnb, wb, WP, bg, q, k, v, g, tb);
    k_attn_out<<<dim3(N/32, N), 256, 0, stream>>>(q, k, v, g, tb, mask, WP + 4*16384, bo, (float*)d_out);
}

// Round 16
// 56.290 us; speedup vs baseline: 1.3428x; 1.0012x over previous
//
#include <hip/hip_runtime.h>
#include <hip/hip_bf16.h>

#define N 192
#define CZ 128
#define NH 4
#define CH 32
#define WIN 16
#define NROWS (N*N)   // 36864

typedef __attribute__((ext_vector_type(8))) short bf16x8;
typedef __attribute__((ext_vector_type(4))) float f32x4;

static __device__ __forceinline__ ushort f2bf(float x){
    union{float f; unsigned u;} a; a.f = x;
    unsigned r = a.u + 0x7fffu + ((a.u>>16)&1u);   // RNE
    return (ushort)(r>>16);
}
static __device__ __forceinline__ float bf2f(ushort s){
    union{unsigned u; float f;} a; a.u = ((unsigned)s)<<16;
    return a.f;
}

// ---------------- K0: pack 5 weight matrices into bf16 MFMA-fragment order ----------------
__global__ __launch_bounds__(256) void k_pack(
    const float* __restrict__ wq, const float* __restrict__ wk,
    const float* __restrict__ wv, const float* __restrict__ wg,
    const float* __restrict__ wo, ushort* __restrict__ WP)
{
    const int m = blockIdx.y;
    const float* W = (m==0)?wq:(m==1)?wk:(m==2)?wv:(m==3)?wg:wo;
    const int f = blockIdx.x*256 + threadIdx.x;     // fragment index 0..2047
    const int nt = f >> 8, ks = (f >> 6) & 3, lane8 = f & 63;
    const int col = nt*16 + (lane8 & 15);
    const int r0  = ks*32 + (lane8 >> 4)*8;
    ushort tmp[8];
    #pragma unroll
    for (int i=0; i<8; i++) tmp[i] = f2bf(W[(size_t)(r0+i)*CZ + col]);
    *(uint4*)(WP + (size_t)m*16384 + (size_t)f*8) = *(uint4*)tmp;
}

// ---------------- K1: LN + triangle-bias projection only (tb is the one non-local dep) ----------------
__global__ __launch_bounds__(256) void k_tb(
    const float* __restrict__ z, const float* __restrict__ lnw, const float* __restrict__ lnb,
    const float* __restrict__ wbias, float* __restrict__ tb)
{
    const int tid = threadIdx.x;
    const int wave = tid >> 6, lane = tid & 63;
    const int r  = wave*4 + (lane >> 4);
    const int li = lane & 15;
    const int row = blockIdx.x*16 + r;
    const float* zr = z + (size_t)row*CZ + li*8;
    float4 a = ((const float4*)zr)[0];
    float4 b = ((const float4*)zr)[1];
    float s  = a.x+a.y+a.z+a.w + b.x+b.y+b.z+b.w;
    float s2 = a.x*a.x+a.y*a.y+a.z*a.z+a.w*a.w + b.x*b.x+b.y*b.y+b.z*b.z+b.w*b.w;
    #pragma unroll
    for (int off=1; off<16; off<<=1) { s += __shfl_xor(s, off); s2 += __shfl_xor(s2, off); }
    const float mu   = s * (1.f/CZ);
    const float rstd = rsqrtf(s2*(1.f/CZ) - mu*mu + 1e-5f);
    const int c0 = li*8;
    float vals[8] = {a.x,a.y,a.z,a.w,b.x,b.y,b.z,b.w};
    float tbp[4] = {0.f,0.f,0.f,0.f};
    #pragma unroll
    for (int t=0; t<8; t++) {
        const float nv = (vals[t]-mu)*rstd*lnw[c0+t] + lnb[c0+t];
        float4 wb4 = *(const float4*)(wbias + (c0+t)*4);
        tbp[0] += nv*wb4.x; tbp[1] += nv*wb4.y;
        tbp[2] += nv*wb4.z; tbp[3] += nv*wb4.w;
    }
    #pragma unroll
    for (int off=1; off<16; off<<=1) {
        #pragma unroll
        for (int h=0; h<4; h++) tbp[h] += __shfl_xor(tbp[h], off);
    }
    if (li == 0) *(float4*)(tb + (size_t)row*4) = make_float4(tbp[0],tbp[1],tbp[2],tbp[3]);
}

// ---------------- K2: fully fused LN + Q/K/V/G proj + attention + gate + out-GEMM ----------------
// Block = (i, j0): 32 output rows + 47-row K/V halo, all LN'd and projected in-LDS.
// No q/k/v/g global buffers at all. z halo reads are L3-hits (z fully L3-resident after k_tb).
__global__ __launch_bounds__(256, 2) void k_fused(
    const float* __restrict__ z, const float* __restrict__ lnw, const float* __restrict__ lnb,
    const float* __restrict__ mask, const float* __restrict__ tb,
    const ushort* __restrict__ WP, const float* __restrict__ bg,
    const float* __restrict__ bout, float* __restrict__ out)
{
    __shared__ ushort zlds[48][132];     // LN'd halo rows, bf16 (+4 pad)
    __shared__ ushort kl[48][NH][40];    // K halo (slot 47 = spill pad, never read)
    __shared__ ushort vl[48][NH][40];
    __shared__ ushort qb[32][136];       // Q for own 32 rows
    __shared__ ushort gb[32][136];       // sigmoid gate
    __shared__ float  ml[48];
    ushort (*po)[136] = (ushort (*)[136])&zlds[0][0];  // gated output; zlds dead by then

    const int i   = blockIdx.y;
    const int j0  = blockIdx.x * 32;
    const int tid = threadIdx.x;
    const int wid = tid >> 6, lane = tid & 63;
    const int l16 = lane & 15, lk = lane >> 4;

    // ---- Phase 1: LN of 48 halo slots (jj = j0-8+r, clamped; masked slots harmless) ----
    for (int it = 0; it < 3; ++it) {
        const int r   = it*16 + wid*4 + lk;
        const int jj  = j0 - 8 + r;
        const int jjc = min(max(jj, 0), N-1);
        const float* zr = z + ((size_t)i*N + jjc)*CZ + l16*8;
        float4 a = ((const float4*)zr)[0];
        float4 b = ((const float4*)zr)[1];
        float s  = a.x+a.y+a.z+a.w + b.x+b.y+b.z+b.w;
        float s2 = a.x*a.x+a.y*a.y+a.z*a.z+a.w*a.w + b.x*b.x+b.y*b.y+b.z*b.z+b.w*b.w;
        #pragma unroll
        for (int off=1; off<16; off<<=1) { s += __shfl_xor(s, off); s2 += __shfl_xor(s2, off); }
        const float mu   = s * (1.f/CZ);
        const float rstd = rsqrtf(s2*(1.f/CZ) - mu*mu + 1e-5f);
        const int c0 = l16*8;
        float vals[8] = {a.x,a.y,a.z,a.w,b.x,b.y,b.z,b.w};
        uint4 pk; ushort* ph = (ushort*)&pk;
        #pragma unroll
        for (int t=0; t<8; t++)
            ph[t] = f2bf((vals[t]-mu)*rstd*lnw[c0+t] + lnb[c0+t]);
        *(uint4*)&zlds[r][c0] = pk;
    }
    if (tid < 47) {
        const int jj  = j0 - 8 + tid;
        const int jjc = min(max(jj, 0), N-1);
        const bool ok = (jj >= 0) && (jj < N) && (mask[(size_t)i*N + jjc] > 0.f);
        ml[tid] = ok ? 0.f : -1e9f;
    }
    __syncthreads();

    // ---- Phase 2: projections from zlds. Wave owns cols [wid*32, wid*32+32). ----
    // K, V over 3 row-tiles (slots 0..47); Q, G over 2 row-tiles (slots 8..39).
    #pragma unroll 1
    for (int m = 1; m <= 2; ++m) {                     // 1=K, 2=V
        bf16x8 bfrag[2][4];
        #pragma unroll
        for (int nt2=0; nt2<2; nt2++)
            #pragma unroll
            for (int ks=0; ks<4; ks++)
                bfrag[nt2][ks] = *(const bf16x8*)(WP + (size_t)m*16384 + (wid*2+nt2)*2048 + ks*512 + lane*8);
        ushort (*dst)[NH][40] = (m==1) ? kl : vl;
        #pragma unroll
        for (int t=0; t<3; ++t) {
            const int slot0 = t*16;
            bf16x8 af[4];
            #pragma unroll
            for (int ks=0; ks<4; ks++)
                af[ks] = *(const bf16x8*)&zlds[slot0 + l16][ks*32 + lk*8];
            #pragma unroll
            for (int nt2=0; nt2<2; nt2++) {
                f32x4 acc = {0.f,0.f,0.f,0.f};
                #pragma unroll
                for (int ks=0; ks<4; ks++)   // swapped -> C^T: row=slot0+l16, cols wid*32+nt2*16+lk*4..+3
                    acc = __builtin_amdgcn_mfma_f32_16x16x32_bf16(bfrag[nt2][ks], af[ks], acc, 0, 0, 0);
                uint2 pk2;
                pk2.x = (unsigned)f2bf(acc[0]) | ((unsigned)f2bf(acc[1])<<16);
                pk2.y = (unsigned)f2bf(acc[2]) | ((unsigned)f2bf(acc[3])<<16);
                *(uint2*)&dst[slot0 + l16][wid][nt2*16 + lk*4] = pk2;
            }
        }
    }
    {   // Q (m=0) and G (m=3) over own rows (slots 8..39 -> qb/gb rows 0..31)
        #pragma unroll 1
        for (int mm = 0; mm < 2; ++mm) {
            const int m = mm ? 3 : 0;
            bf16x8 bfrag[2][4];
            float4 bg4[2];
            #pragma unroll
            for (int nt2=0; nt2<2; nt2++) {
                #pragma unroll
                for (int ks=0; ks<4; ks++)
                    bfrag[nt2][ks] = *(const bf16x8*)(WP + (size_t)m*16384 + (wid*2+nt2)*2048 + ks*512 + lane*8);
                if (mm) bg4[nt2] = *(const float4*)(bg + wid*32 + nt2*16 + lk*4);
            }
            #pragma unroll
            for (int t=0; t<2; ++t) {
                const int slot0 = 8 + t*16;
                bf16x8 af[4];
                #pragma unroll
                for (int ks=0; ks<4; ks++)
                    af[ks] = *(const bf16x8*)&zlds[slot0 + l16][ks*32 + lk*8];
                #pragma unroll
                for (int nt2=0; nt2<2; nt2++) {
                    f32x4 acc = {0.f,0.f,0.f,0.f};
                    #pragma unroll
                    for (int ks=0; ks<4; ks++)
                        acc = __builtin_amdgcn_mfma_f32_16x16x32_bf16(bfrag[nt2][ks], af[ks], acc, 0, 0, 0);
                    float v0,v1,v2,v3;
                    if (mm) {
                        v0 = 1.f/(1.f + __expf(-(acc[0] + bg4[nt2].x)));
                        v1 = 1.f/(1.f + __expf(-(acc[1] + bg4[nt2].y)));
                        v2 = 1.f/(1.f + __expf(-(acc[2] + bg4[nt2].z)));
                        v3 = 1.f/(1.f + __expf(-(acc[3] + bg4[nt2].w)));
                    } else { v0=acc[0]; v1=acc[1]; v2=acc[2]; v3=acc[3]; }
                    uint2 pk2;
                    pk2.x = (unsigned)f2bf(v0) | ((unsigned)f2bf(v1)<<16);
                    pk2.y = (unsigned)f2bf(v2) | ((unsigned)f2bf(v3)<<16);
                    if (mm) *(uint2*)&gb[t*16 + l16][wid*32 + nt2*16 + lk*4] = pk2;
                    else    *(uint2*)&qb[t*16 + l16][wid*32 + nt2*16 + lk*4] = pk2;
                }
            }
        }
    }
    __syncthreads();

    // ---- Phase 3: windowed attention (thread = (jloc, h, chalf)) ----
    const int chalf = tid & 1;
    const int h     = (tid >> 1) & 3;
    const int jloc  = tid >> 3;
    const int j     = j0 + jloc;
    const int c0l   = chalf * 16;

    float qv[16];
    {
        uint4 q1 = *(const uint4*)&qb[jloc][h*CH + c0l];
        uint4 q2 = *(const uint4*)&qb[jloc][h*CH + c0l + 8];
        const ushort* s1 = (const ushort*)&q1;
        const ushort* s2 = (const ushort*)&q2;
        #pragma unroll
        for (int t=0; t<8; t++) { qv[t] = bf2f(s1[t]); qv[8+t] = bf2f(s2[t]); }
    }

    const float scale = 0.17677669529663688f; // 1/sqrt(32)
    float lg[WIN];
    #pragma unroll
    for (int w=0; w<WIN; w++) {
        const int rel = jloc + w;
        float dot = 0.f;
        #pragma unroll
        for (int c4=0; c4<2; c4++) {
            uint4 kv = *(const uint4*)&kl[rel][h][c0l + c4*8];
            const ushort* kp = (const ushort*)&kv;
            #pragma unroll
            for (int t=0; t<8; t++) dot += qv[c4*8+t]*bf2f(kp[t]);
        }
        dot += __shfl_xor(dot, 1);
        const int jj  = j - 8 + w;
        const int jjc = min(max(jj, 0), N-1);
        lg[w] = dot*scale + tb[((size_t)j*N + jjc)*4 + h] + ml[rel];
    }
    float mx = lg[0];
    #pragma unroll
    for (int w=1; w<WIN; w++) mx = fmaxf(mx, lg[w]);
    float sum = 0.f;
    #pragma unroll
    for (int w=0; w<WIN; w++) { lg[w] = __expf(lg[w]-mx); sum += lg[w]; }
    const float inv = 1.f/sum;

    float o[16];
    #pragma unroll
    for (int c=0; c<16; c++) o[c] = 0.f;
    #pragma unroll
    for (int w=0; w<WIN; w++) {
        const float p   = lg[w]*inv;
        const int   rel = jloc + w;
        #pragma unroll
        for (int c4=0; c4<2; c4++) {
            uint4 vv = *(const uint4*)&vl[rel][h][c0l + c4*8];
            const ushort* vp = (const ushort*)&vv;
            #pragma unroll
            for (int t=0; t<8; t++) o[c4*8+t] += p*bf2f(vp[t]);
        }
    }

    uint4 o1, o2;
    {
        uint4 g1 = *(const uint4*)&gb[jloc][h*CH + c0l];
        uint4 g2 = *(const uint4*)&gb[jloc][h*CH + c0l + 8];
        const ushort* s1 = (const ushort*)&g1;
        const ushort* s2 = (const ushort*)&g2;
        ushort* p1 = (ushort*)&o1; ushort* p2 = (ushort*)&o2;
        #pragma unroll
        for (int t=0; t<8; t++) {
            p1[t] = f2bf(o[t]   * bf2f(s1[t]));
            p2[t] = f2bf(o[8+t] * bf2f(s2[t]));
        }
    }
    *(uint4*)&po[jloc][h*CH + c0l]     = o1;   // po aliases zlds (dead since phase 2)
    *(uint4*)&po[jloc][h*CH + c0l + 8] = o2;

    // ---- Phase 4: out-GEMM, packed-B ----
    bf16x8 bfrag[2][4];
    float4 bo4[2];
    #pragma unroll
    for (int nt2=0; nt2<2; nt2++) {
        #pragma unroll
        for (int ks=0; ks<4; ks++)
            bfrag[nt2][ks] = *(const bf16x8*)(WP + (size_t)4*16384 + (wid*2+nt2)*2048 + ks*512 + lane*8);
        bo4[nt2] = *(const float4*)(bout + wid*32 + nt2*16 + lk*4);
    }
    __syncthreads();

    #pragma unroll
    for (int rt=0; rt<2; rt++) {
        bf16x8 af[4];
        #pragma unroll
        for (int ks=0; ks<4; ks++)
            af[ks] = *(const bf16x8*)&po[rt*16 + l16][ks*32 + lk*8];
        const size_t orow = (size_t)(i*N + j0 + rt*16 + l16)*CZ;
        #pragma unroll
        for (int nt2=0; nt2<2; nt2++) {
            f32x4 acc = {0.f,0.f,0.f,0.f};
            #pragma unroll
            for (int ks=0; ks<4; ks++)   // swapped -> C^T: row=l16, 4 consecutive cols
                acc = __builtin_amdgcn_mfma_f32_16x16x32_bf16(bfrag[nt2][ks], af[ks], acc, 0, 0, 0);
            float4 ov;
            ov.x = acc[0] + bo4[nt2].x; ov.y = acc[1] + bo4[nt2].y;
            ov.z = acc[2] + bo4[nt2].z; ov.w = acc[3] + bo4[nt2].w;
            *(float4*)(out + orow + wid*32 + nt2*16 + lk*4) = ov;
        }
    }
}

extern "C" void kernel_launch(void* const* d_in, const int* in_sizes, int n_in,
                              void* d_out, int out_size, void* d_ws, size_t ws_size,
                              hipStream_t stream)
{
    const float* z    = (const float*)d_in[0];
    const float* mask = (const float*)d_in[1];
    const float* lnw  = (const float*)d_in[2];
    const float* lnb  = (const float*)d_in[3];
    const float* wq   = (const float*)d_in[4];
    const float* wk   = (const float*)d_in[5];
    const float* wv   = (const float*)d_in[6];
    const float* wb   = (const float*)d_in[7];
    const float* wg   = (const float*)d_in[8];
    const float* bg   = (const float*)d_in[9];
    const float* wo   = (const float*)d_in[10];
    const float* bo   = (const float*)d_in[11];

    float*  tb = (float*)d_ws;                      // f32 [NROWS][4]
    ushort* WP = (ushort*)(tb + (size_t)NROWS*4);   // 5 x 16384 bf16, fragment-ordered
    if (ws_size < (size_t)NROWS*4*sizeof(float) + 5*16384*sizeof(ushort)) return;

    k_pack <<<dim3(8,5), 256, 0, stream>>>(wq, wk, wv, wg, wo, WP);
    k_tb   <<<NROWS/16, 256, 0, stream>>>(z, lnw, lnb, wb, tb);
    k_fused<<<dim3(N/32, N), 256, 0, stream>>>(z, lnw, lnb, mask, tb, WP, bg, bo, (float*)d_out);
}

// Round 17
// 54.633 us; speedup vs baseline: 1.3835x; 1.0303x over previous
//
#include <hip/hip_runtime.h>
#include <hip/hip_bf16.h>

#define N 192
#define CZ 128
#define NH 4
#define CH 32
#define WIN 16
#define NROWS (N*N)   // 36864

typedef __attribute__((ext_vector_type(8))) short bf16x8;
typedef __attribute__((ext_vector_type(4))) float f32x4;

static __device__ __forceinline__ ushort f2bf(float x){
    union{float f; unsigned u;} a; a.f = x;
    unsigned r = a.u + 0x7fffu + ((a.u>>16)&1u);   // RNE
    return (ushort)(r>>16);
}
static __device__ __forceinline__ float bf2f(ushort s){
    union{unsigned u; float f;} a; a.u = ((unsigned)s)<<16;
    return a.f;
}

// ---------------- K0: pack 5 weight matrices into bf16 MFMA-fragment order ----------------
__global__ __launch_bounds__(256) void k_pack(
    const float* __restrict__ wq, const float* __restrict__ wk,
    const float* __restrict__ wv, const float* __restrict__ wg,
    const float* __restrict__ wo, ushort* __restrict__ WP)
{
    const int m = blockIdx.y;
    const float* W = (m==0)?wq:(m==1)?wk:(m==2)?wv:(m==3)?wg:wo;
    const int f = blockIdx.x*256 + threadIdx.x;     // fragment index 0..2047
    const int nt = f >> 8, ks = (f >> 6) & 3, lane8 = f & 63;
    const int col = nt*16 + (lane8 & 15);
    const int r0  = ks*32 + (lane8 >> 4)*8;
    ushort tmp[8];
    #pragma unroll
    for (int i=0; i<8; i++) tmp[i] = f2bf(W[(size_t)(r0+i)*CZ + col]);
    *(uint4*)(WP + (size_t)m*16384 + (size_t)f*8) = *(uint4*)tmp;
}

// ---------------- K1: LN + triangle-bias projection (the one non-local dep) ----------------
__global__ __launch_bounds__(256) void k_tb(
    const float* __restrict__ z, const float* __restrict__ lnw, const float* __restrict__ lnb,
    const float* __restrict__ wbias, float* __restrict__ tb)
{
    const int tid = threadIdx.x;
    const int wave = tid >> 6, lane = tid & 63;
    const int r  = wave*4 + (lane >> 4);
    const int li = lane & 15;
    const int row = blockIdx.x*16 + r;
    const float* zr = z + (size_t)row*CZ + li*8;
    float4 a = ((const float4*)zr)[0];
    float4 b = ((const float4*)zr)[1];
    float s  = a.x+a.y+a.z+a.w + b.x+b.y+b.z+b.w;
    float s2 = a.x*a.x+a.y*a.y+a.z*a.z+a.w*a.w + b.x*b.x+b.y*b.y+b.z*b.z+b.w*b.w;
    #pragma unroll
    for (int off=1; off<16; off<<=1) { s += __shfl_xor(s, off); s2 += __shfl_xor(s2, off); }
    const float mu   = s * (1.f/CZ);
    const float rstd = rsqrtf(s2*(1.f/CZ) - mu*mu + 1e-5f);
    const int c0 = li*8;
    float vals[8] = {a.x,a.y,a.z,a.w,b.x,b.y,b.z,b.w};
    float tbp[4] = {0.f,0.f,0.f,0.f};
    #pragma unroll
    for (int t=0; t<8; t++) {
        const float nv = (vals[t]-mu)*rstd*lnw[c0+t] + lnb[c0+t];
        float4 wb4 = *(const float4*)(wbias + (c0+t)*4);
        tbp[0] += nv*wb4.x; tbp[1] += nv*wb4.y;
        tbp[2] += nv*wb4.z; tbp[3] += nv*wb4.w;
    }
    #pragma unroll
    for (int off=1; off<16; off<<=1) {
        #pragma unroll
        for (int h=0; h<4; h++) tbp[h] += __shfl_xor(tbp[h], off);
    }
    if (li == 0) *(float4*)(tb + (size_t)row*4) = make_float4(tbp[0],tbp[1],tbp[2],tbp[3]);
}

// ---------------- K2: fused LN + Q/K/V/G proj + attention + gate + out-GEMM ----------------
// 512 threads (8 waves): same 61KB LDS as R16 but 2x waves/SIMD (4 vs 2) for latency hiding.
__global__ __launch_bounds__(512, 4) void k_fused(
    const float* __restrict__ z, const float* __restrict__ lnw, const float* __restrict__ lnb,
    const float* __restrict__ mask, const float* __restrict__ tb,
    const ushort* __restrict__ WP, const float* __restrict__ bg,
    const float* __restrict__ bout, float* __restrict__ out)
{
    __shared__ ushort zlds[48][132];     // LN'd halo rows, bf16 (+4 pad)
    __shared__ ushort kl[48][NH][40];    // K halo (slot 47 = spill pad, never read)
    __shared__ ushort vl[48][NH][40];
    __shared__ ushort qb[32][136];       // Q for own 32 rows
    __shared__ ushort gb[32][136];       // sigmoid gate
    __shared__ float  ml[48];
    ushort (*po)[136] = (ushort (*)[136])&zlds[0][0];  // gated output; zlds dead by then

    const int i   = blockIdx.y;
    const int j0  = blockIdx.x * 32;
    const int tid = threadIdx.x;
    const int wid = tid >> 6, lane = tid & 63;
    const int l16 = lane & 15, lk = lane >> 4;

    // ---- Phase 1: LN of 48 halo slots (2 passes of 32 rows; 16 lanes x 8ch per row) ----
    #pragma unroll
    for (int pass = 0; pass < 2; ++pass) {
        const int r = pass*32 + (tid >> 4);
        if (r < 48) {
            const int li  = tid & 15;
            const int jj  = j0 - 8 + r;
            const int jjc = min(max(jj, 0), N-1);
            const float* zr = z + ((size_t)i*N + jjc)*CZ + li*8;
            float4 a = ((const float4*)zr)[0];
            float4 b = ((const float4*)zr)[1];
            float s  = a.x+a.y+a.z+a.w + b.x+b.y+b.z+b.w;
            float s2 = a.x*a.x+a.y*a.y+a.z*a.z+a.w*a.w + b.x*b.x+b.y*b.y+b.z*b.z+b.w*b.w;
            #pragma unroll
            for (int off=1; off<16; off<<=1) { s += __shfl_xor(s, off); s2 += __shfl_xor(s2, off); }
            const float mu   = s * (1.f/CZ);
            const float rstd = rsqrtf(s2*(1.f/CZ) - mu*mu + 1e-5f);
            const int c0 = li*8;
            float vals[8] = {a.x,a.y,a.z,a.w,b.x,b.y,b.z,b.w};
            uint4 pk; ushort* ph = (ushort*)&pk;
            #pragma unroll
            for (int t=0; t<8; t++)
                ph[t] = f2bf((vals[t]-mu)*rstd*lnw[c0+t] + lnb[c0+t]);
            *(uint4*)&zlds[r][c0] = pk;
        }
    }
    if (tid < 47) {
        const int jj  = j0 - 8 + tid;
        const int jjc = min(max(jj, 0), N-1);
        const bool ok = (jj >= 0) && (jj < N) && (mask[(size_t)i*N + jjc] > 0.f);
        ml[tid] = ok ? 0.f : -1e9f;
    }
    __syncthreads();

    // ---- Phase 2: projections. 10 tile-jobs split over 8 waves (5 per half). ----
    {
        const int cw   = wid & 3;     // column quarter (= head for kl/vl)
        const int half = wid >> 2;

        bf16x8 bfrag[2][4];
        auto loadB = [&](int m) {
            #pragma unroll
            for (int nt2=0; nt2<2; nt2++)
                #pragma unroll
                for (int ks=0; ks<4; ks++)
                    bfrag[nt2][ks] = *(const bf16x8*)(WP + (size_t)m*16384 + (cw*2+nt2)*2048 + ks*512 + lane*8);
        };
        auto projKV = [&](int slot0, ushort (*dst)[NH][40]) {
            bf16x8 af[4];
            #pragma unroll
            for (int ks=0; ks<4; ks++)
                af[ks] = *(const bf16x8*)&zlds[slot0 + l16][ks*32 + lk*8];
            #pragma unroll
            for (int nt2=0; nt2<2; nt2++) {
                f32x4 acc = {0.f,0.f,0.f,0.f};
                #pragma unroll
                for (int ks=0; ks<4; ks++)   // swapped -> C^T: row=slot0+l16
                    acc = __builtin_amdgcn_mfma_f32_16x16x32_bf16(bfrag[nt2][ks], af[ks], acc, 0, 0, 0);
                uint2 pk2;
                pk2.x = (unsigned)f2bf(acc[0]) | ((unsigned)f2bf(acc[1])<<16);
                pk2.y = (unsigned)f2bf(acc[2]) | ((unsigned)f2bf(acc[3])<<16);
                *(uint2*)&dst[slot0 + l16][cw][nt2*16 + lk*4] = pk2;
            }
        };
        auto projQG = [&](int slot0, ushort (*dst)[136], bool gate) {
            float4 bg4[2];
            if (gate)
                #pragma unroll
                for (int nt2=0; nt2<2; nt2++)
                    bg4[nt2] = *(const float4*)(bg + cw*32 + nt2*16 + lk*4);
            bf16x8 af[4];
            #pragma unroll
            for (int ks=0; ks<4; ks++)
                af[ks] = *(const bf16x8*)&zlds[slot0 + l16][ks*32 + lk*8];
            #pragma unroll
            for (int nt2=0; nt2<2; nt2++) {
                f32x4 acc = {0.f,0.f,0.f,0.f};
                #pragma unroll
                for (int ks=0; ks<4; ks++)
                    acc = __builtin_amdgcn_mfma_f32_16x16x32_bf16(bfrag[nt2][ks], af[ks], acc, 0, 0, 0);
                float v0,v1,v2,v3;
                if (gate) {
                    v0 = 1.f/(1.f + __expf(-(acc[0] + bg4[nt2].x)));
                    v1 = 1.f/(1.f + __expf(-(acc[1] + bg4[nt2].y)));
                    v2 = 1.f/(1.f + __expf(-(acc[2] + bg4[nt2].z)));
                    v3 = 1.f/(1.f + __expf(-(acc[3] + bg4[nt2].w)));
                } else { v0=acc[0]; v1=acc[1]; v2=acc[2]; v3=acc[3]; }
                uint2 pk2;
                pk2.x = (unsigned)f2bf(v0) | ((unsigned)f2bf(v1)<<16);
                pk2.y = (unsigned)f2bf(v2) | ((unsigned)f2bf(v3)<<16);
                *(uint2*)&dst[slot0 - 8 + l16][cw*32 + nt2*16 + lk*4] = pk2;
            }
        };

        if (half == 0) {
            loadB(1); projKV(0, kl); projKV(16, kl); projKV(32, kl);   // K
            loadB(2); projKV(0, vl); projKV(16, vl);                   // V (part)
        } else {
            loadB(2); projKV(32, vl);                                  // V (rest)
            loadB(0); projQG(8, qb, false); projQG(24, qb, false);     // Q
            loadB(3); projQG(8, gb, true);  projQG(24, gb, true);      // G
        }
    }
    __syncthreads();

    // ---- Phase 3: windowed attention (thread = (jloc, h, cq)): 8 channels each ----
    const int cq   = tid & 3;
    const int h    = (tid >> 2) & 3;
    const int jloc = tid >> 4;
    const int j    = j0 + jloc;
    const int c0l  = cq * 8;

    float qv[8];
    {
        uint4 q1 = *(const uint4*)&qb[jloc][h*CH + c0l];
        const ushort* s1 = (const ushort*)&q1;
        #pragma unroll
        for (int t=0; t<8; t++) qv[t] = bf2f(s1[t]);
    }

    const float scale = 0.17677669529663688f; // 1/sqrt(32)
    float lg[WIN];
    #pragma unroll
    for (int w=0; w<WIN; w++) {
        const int rel = jloc + w;
        float dot = 0.f;
        {
            uint4 kv = *(const uint4*)&kl[rel][h][c0l];
            const ushort* kp = (const ushort*)&kv;
            #pragma unroll
            for (int t=0; t<8; t++) dot += qv[t]*bf2f(kp[t]);
        }
        dot += __shfl_xor(dot, 1);
        dot += __shfl_xor(dot, 2);          // combine the four c-quarters
        const int jj  = j - 8 + w;
        const int jjc = min(max(jj, 0), N-1);
        lg[w] = dot*scale + tb[((size_t)j*N + jjc)*4 + h] + ml[rel];
    }
    float mx = lg[0];
    #pragma unroll
    for (int w=1; w<WIN; w++) mx = fmaxf(mx, lg[w]);
    float sum = 0.f;
    #pragma unroll
    for (int w=0; w<WIN; w++) { lg[w] = __expf(lg[w]-mx); sum += lg[w]; }
    const float inv = 1.f/sum;

    float o[8];
    #pragma unroll
    for (int c=0; c<8; c++) o[c] = 0.f;
    #pragma unroll
    for (int w=0; w<WIN; w++) {
        const float p   = lg[w]*inv;
        const int   rel = jloc + w;
        uint4 vv = *(const uint4*)&vl[rel][h][c0l];
        const ushort* vp = (const ushort*)&vv;
        #pragma unroll
        for (int t=0; t<8; t++) o[t] += p*bf2f(vp[t]);
    }

    {
        uint4 g1 = *(const uint4*)&gb[jloc][h*CH + c0l];
        const ushort* s1 = (const ushort*)&g1;
        uint4 o1; ushort* p1 = (ushort*)&o1;
        #pragma unroll
        for (int t=0; t<8; t++) p1[t] = f2bf(o[t] * bf2f(s1[t]));
        *(uint4*)&po[jloc][h*CH + c0l] = o1;   // po aliases zlds (dead since phase 2)
    }

    // ---- Phase 4: out-GEMM. Wave = (rt, col-quarter): 1 row-tile x 32 cols each ----
    const int rt  = wid >> 2;
    const int cwo = wid & 3;
    bf16x8 bfrag[2][4];
    float4 bo4[2];
    #pragma unroll
    for (int nt2=0; nt2<2; nt2++) {
        #pragma unroll
        for (int ks=0; ks<4; ks++)
            bfrag[nt2][ks] = *(const bf16x8*)(WP + (size_t)4*16384 + (cwo*2+nt2)*2048 + ks*512 + lane*8);
        bo4[nt2] = *(const float4*)(bout + cwo*32 + nt2*16 + lk*4);
    }
    __syncthreads();

    {
        bf16x8 af[4];
        #pragma unroll
        for (int ks=0; ks<4; ks++)
            af[ks] = *(const bf16x8*)&po[rt*16 + l16][ks*32 + lk*8];
        const size_t orow = (size_t)(i*N + j0 + rt*16 + l16)*CZ;
        #pragma unroll
        for (int nt2=0; nt2<2; nt2++) {
            f32x4 acc = {0.f,0.f,0.f,0.f};
            #pragma unroll
            for (int ks=0; ks<4; ks++)   // swapped -> C^T: row=l16, 4 consecutive cols
                acc = __builtin_amdgcn_mfma_f32_16x16x32_bf16(bfrag[nt2][ks], af[ks], acc, 0, 0, 0);
            float4 ov;
            ov.x = acc[0] + bo4[nt2].x; ov.y = acc[1] + bo4[nt2].y;
            ov.z = acc[2] + bo4[nt2].z; ov.w = acc[3] + bo4[nt2].w;
            *(float4*)(out + orow + cwo*32 + nt2*16 + lk*4) = ov;
        }
    }
}

extern "C" void kernel_launch(void* const* d_in, const int* in_sizes, int n_in,
                              void* d_out, int out_size, void* d_ws, size_t ws_size,
                              hipStream_t stream)
{
    const float* z    = (const float*)d_in[0];
    const float* mask = (const float*)d_in[1];
    const float* lnw  = (const float*)d_in[2];
    const float* lnb  = (const float*)d_in[3];
    const float* wq   = (const float*)d_in[4];
    const float* wk   = (const float*)d_in[5];
    const float* wv   = (const float*)d_in[6];
    const float* wb   = (const float*)d_in[7];
    const float* wg   = (const float*)d_in[8];
    const float* bg   = (const float*)d_in[9];
    const float* wo   = (const float*)d_in[10];
    const float* bo   = (const float*)d_in[11];

    float*  tb = (float*)d_ws;                      // f32 [NROWS][4]
    ushort* WP = (ushort*)(tb + (size_t)NROWS*4);   // 5 x 16384 bf16, fragment-ordered
    if (ws_size < (size_t)NROWS*4*sizeof(float) + 5*16384*sizeof(ushort)) return;

    k_pack <<<dim3(8,5), 256, 0, stream>>>(wq, wk, wv, wg, wo, WP);
    k_tb   <<<NROWS/16, 256, 0, stream>>>(z, lnw, lnb, wb, tb);
    k_fused<<<dim3(N/32, N), 512, 0, stream>>>(z, lnw, lnb, mask, tb, WP, bg, bo, (float*)d_out);
}